// Round 2
// baseline (509.221 us; speedup 1.0000x reference)
//
#include <hip/hip_runtime.h>
#include <hip/hip_bf16.h>

#define NNODES 50000

// ---------------- graph preprocessing ----------------

__global__ __launch_bounds__(256) void k_count(const int* __restrict__ dst,
                                               int* __restrict__ cnt, int E) {
    int e = blockIdx.x * 256 + threadIdx.x;
    if (e < E) atomicAdd(&cnt[dst[e]], 1);
}

__global__ __launch_bounds__(256) void k_dinv(const int* __restrict__ cnt,
                                              float* __restrict__ dinv, int N) {
    int i = blockIdx.x * 256 + threadIdx.x;
    if (i < N) dinv[i] = rsqrtf((float)cnt[i] + 1.0f);  // +1 self-loop; deg>=1 always
}

// single-block exclusive scan of cnt[N] -> offs[N+1], also seeds cursor
__global__ __launch_bounds__(1024) void k_scan(const int* __restrict__ cnt,
                                               int* __restrict__ offs,
                                               int* __restrict__ cursor, int N) {
    __shared__ int part[1024];
    int t = threadIdx.x;
    int chunk = (N + 1023) >> 10;
    int start = t * chunk;
    int end = min(start + chunk, N);
    int s = 0;
    for (int i = start; i < end; ++i) s += cnt[i];
    part[t] = s;
    __syncthreads();
    for (int o = 1; o < 1024; o <<= 1) {
        int v = (t >= o) ? part[t - o] : 0;
        __syncthreads();
        part[t] += v;
        __syncthreads();
    }
    int run = part[t] - s;  // exclusive prefix
    for (int i = start; i < end; ++i) {
        offs[i] = run;
        cursor[i] = run;
        run += cnt[i];
    }
    if (t == 1023) offs[N] = part[1023];
}

__global__ __launch_bounds__(256) void k_scatter(const int* __restrict__ src,
                                                 const int* __restrict__ dst,
                                                 const float* __restrict__ dinv,
                                                 int* __restrict__ cursor,
                                                 int* __restrict__ csr_src,
                                                 float* __restrict__ csr_norm, int E) {
    int e = blockIdx.x * 256 + threadIdx.x;
    if (e >= E) return;
    int s = src[e], d = dst[e];
    int pos = atomicAdd(&cursor[d], 1);
    csr_src[pos] = s;
    csr_norm[pos] = dinv[s] * dinv[d];
}

// ---------------- dense: Y[n,128] = X[n,128] @ W[128,128] (fp32) ----------------

__global__ __launch_bounds__(256) void k_gemm128(const float* __restrict__ X,
                                                 const float* __restrict__ W,
                                                 float* __restrict__ Y, int n) {
    __shared__ float wl[64 * 128];  // 32 KB: half of W
    __shared__ float xl[16 * 128];  // 8 KB: 16-node x tile
    int t = threadIdx.x;
    int base = blockIdx.x * 16;
    for (int idx = t; idx < 16 * 128; idx += 256) {
        int node = base + (idx >> 7);
        xl[idx] = (node < n) ? X[(size_t)node * 128 + (idx & 127)] : 0.0f;
    }
    int col = t & 127;
    int half = t >> 7;
    float acc[8];
#pragma unroll
    for (int r = 0; r < 8; ++r) acc[r] = 0.0f;

    for (int phase = 0; phase < 2; ++phase) {
        __syncthreads();  // xl ready (phase 0) / previous wl reads done (phase 1)
        for (int idx = t; idx < 64 * 128; idx += 256)
            wl[idx] = W[phase * 64 * 128 + idx];
        __syncthreads();
        for (int k2 = 0; k2 < 64; ++k2) {
            float wv = wl[k2 * 128 + col];         // consecutive cols: conflict-free
            int k = phase * 64 + k2;
#pragma unroll
            for (int r = 0; r < 8; ++r)            // xl read is wave-broadcast (free)
                acc[r] = fmaf(xl[(r * 2 + half) * 128 + k], wv, acc[r]);
        }
    }
#pragma unroll
    for (int r = 0; r < 8; ++r) {
        int node = base + r * 2 + half;
        if (node < n) Y[(size_t)node * 128 + col] = acc[r];
    }
}

// ---------------- sparse aggregation + bias + relu ----------------

__global__ __launch_bounds__(256) void k_aggregate(const float2* __restrict__ xw2,
                                                   const int* __restrict__ offs,
                                                   const int* __restrict__ csr_src,
                                                   const float* __restrict__ csr_norm,
                                                   const float* __restrict__ dinv,
                                                   const float* __restrict__ bias,
                                                   float* __restrict__ out, int n) {
    int lane = threadIdx.x & 63;
    int i = (blockIdx.x * 256 + threadIdx.x) >> 6;  // one wave per node
    if (i >= n) return;
    float di = dinv[i];
    float sn = di * di;                              // self-loop norm
    float2 v0 = xw2[(size_t)i * 64 + lane];
    float ax = v0.x * sn, ay = v0.y * sn;
    int beg = offs[i], fin = offs[i + 1];
    for (int j = beg; j < fin; ++j) {
        int s = csr_src[j];                          // wave-broadcast reads
        float w = csr_norm[j];
        float2 u = xw2[(size_t)s * 64 + lane];       // 512 B coalesced row gather
        ax = fmaf(u.x, w, ax);
        ay = fmaf(u.y, w, ay);
    }
    float bx = bias[lane * 2], by = bias[lane * 2 + 1];
    ax = fmaxf(ax + bx, 0.0f);
    ay = fmaxf(ay + by, 0.0f);
    ((float2*)out)[(size_t)i * 64 + lane] = make_float2(ax, ay);
}

// ---------------- launch ----------------

extern "C" void kernel_launch(void* const* d_in, const int* in_sizes, int n_in,
                              void* d_out, int out_size, void* d_ws, size_t ws_size,
                              hipStream_t stream) {
    const float* x  = (const float*)d_in[0];
    const int*   ei = (const int*)d_in[1];
    const float* W1 = (const float*)d_in[2];
    const float* b1 = (const float*)d_in[3];
    const float* W2 = (const float*)d_in[4];
    const float* b2 = (const float*)d_in[5];
    float* out = (float*)d_out;

    const int N = NNODES;
    const int E = in_sizes[1] / 2;  // 625000
    const int* src = ei;
    const int* dst = ei + E;

    char* p = (char*)d_ws;
    size_t off = 0;
    auto take = [&](size_t bytes) -> void* {
        void* r = p + off;
        off = (off + bytes + 255) & ~(size_t)255;
        return r;
    };
    int*   cnt      = (int*)  take((size_t)N * 4);
    int*   offs     = (int*)  take((size_t)(N + 1) * 4);
    int*   cursor   = (int*)  take((size_t)N * 4);
    float* dinv     = (float*)take((size_t)N * 4);
    int*   csr_src  = (int*)  take((size_t)E * 4);
    float* csr_norm = (float*)take((size_t)E * 4);
    float* xw       = (float*)take((size_t)N * 128 * 4);
    float* h        = (float*)take((size_t)N * 128 * 4);

    // graph preprocessing (shared by both layers)
    hipMemsetAsync(cnt, 0, (size_t)N * 4, stream);
    k_count<<<(E + 255) / 256, 256, 0, stream>>>(dst, cnt, E);
    k_dinv<<<(N + 255) / 256, 256, 0, stream>>>(cnt, dinv, N);
    k_scan<<<1, 1024, 0, stream>>>(cnt, offs, cursor, N);
    k_scatter<<<(E + 255) / 256, 256, 0, stream>>>(src, dst, dinv, cursor,
                                                   csr_src, csr_norm, E);

    // layer 1: h = relu(Ahat @ (x@W1) + b1)
    k_gemm128<<<(N + 15) / 16, 256, 0, stream>>>(x, W1, xw, N);
    k_aggregate<<<(N * 64 + 255) / 256, 256, 0, stream>>>(
        (const float2*)xw, offs, csr_src, csr_norm, dinv, b1, h, N);

    // layer 2: out = relu(Ahat @ (h@W2) + b2)
    k_gemm128<<<(N + 15) / 16, 256, 0, stream>>>(h, W2, xw, N);
    k_aggregate<<<(N * 64 + 255) / 256, 256, 0, stream>>>(
        (const float2*)xw, offs, csr_src, csr_norm, dinv, b2, out, N);
}

// Round 3
// 407.172 us; speedup vs baseline: 1.2506x; 1.2506x over previous
//
#include <hip/hip_runtime.h>
#include <hip/hip_bf16.h>

#define NNODES 50000

// ---------------- graph preprocessing ----------------

__global__ __launch_bounds__(256) void k_count(const int* __restrict__ dst,
                                               int* __restrict__ cnt, int E) {
    int e = blockIdx.x * 256 + threadIdx.x;
    if (e < E) atomicAdd(&cnt[dst[e]], 1);
}

__global__ __launch_bounds__(256) void k_dinv(const int* __restrict__ cnt,
                                              float* __restrict__ dinv, int N) {
    int i = blockIdx.x * 256 + threadIdx.x;
    if (i < N) dinv[i] = rsqrtf((float)cnt[i] + 1.0f);  // +1 self-loop; deg>=1 always
}

// ---- hierarchical exclusive scan of cnt[N] -> offs[N+1] (3 kernels) ----

// per-block exclusive scan; block totals to bsum
__global__ __launch_bounds__(256) void k_scan1(const int* __restrict__ cnt,
                                               int* __restrict__ offs,
                                               int* __restrict__ bsum, int N) {
    __shared__ int sh[256];
    int t = threadIdx.x;
    int i = blockIdx.x * 256 + t;
    int v = (i < N) ? cnt[i] : 0;
    sh[t] = v;
    __syncthreads();
#pragma unroll
    for (int o = 1; o < 256; o <<= 1) {
        int u = (t >= o) ? sh[t - o] : 0;
        __syncthreads();
        sh[t] += u;
        __syncthreads();
    }
    if (i < N) offs[i] = sh[t] - v;  // local exclusive
    if (t == 255) bsum[blockIdx.x] = sh[255];
}

// single tiny block: exclusive scan of block sums (NB <= 256)
__global__ __launch_bounds__(256) void k_scan2(int* __restrict__ bsum, int NB) {
    __shared__ int sh[256];
    int t = threadIdx.x;
    int v = (t < NB) ? bsum[t] : 0;
    sh[t] = v;
    __syncthreads();
#pragma unroll
    for (int o = 1; o < 256; o <<= 1) {
        int u = (t >= o) ? sh[t - o] : 0;
        __syncthreads();
        sh[t] += u;
        __syncthreads();
    }
    if (t < NB) bsum[t] = sh[t] - v;  // exclusive
}

// add-back + cursor seed; offs[N] = E (statically known: every dst in [0,N))
__global__ __launch_bounds__(256) void k_scan3(int* __restrict__ offs,
                                               const int* __restrict__ bsum,
                                               int* __restrict__ cursor, int N, int E) {
    int i = blockIdx.x * 256 + threadIdx.x;
    if (i < N) {
        int o = offs[i] + bsum[blockIdx.x];
        offs[i] = o;
        cursor[i] = o;
    }
    if (i == 0) offs[N] = E;
}

__global__ __launch_bounds__(256) void k_scatter(const int* __restrict__ src,
                                                 const int* __restrict__ dst,
                                                 const float* __restrict__ dinv,
                                                 int* __restrict__ cursor,
                                                 int* __restrict__ csr_src,
                                                 float* __restrict__ csr_norm, int E) {
    int e = blockIdx.x * 256 + threadIdx.x;
    if (e >= E) return;
    int s = src[e], d = dst[e];
    int pos = atomicAdd(&cursor[d], 1);
    csr_src[pos] = s;
    csr_norm[pos] = dinv[s] * dinv[d];
}

// ---------------- dense: Y[n,128] = X[n,128] @ W[128,128] (fp32) ----------------

__global__ __launch_bounds__(256) void k_gemm128(const float* __restrict__ X,
                                                 const float* __restrict__ W,
                                                 float* __restrict__ Y, int n) {
    __shared__ float wl[64 * 128];  // 32 KB: half of W
    __shared__ float xl[16 * 128];  // 8 KB: 16-node x tile
    int t = threadIdx.x;
    int base = blockIdx.x * 16;
    for (int idx = t; idx < 16 * 128; idx += 256) {
        int node = base + (idx >> 7);
        xl[idx] = (node < n) ? X[(size_t)node * 128 + (idx & 127)] : 0.0f;
    }
    int col = t & 127;
    int half = t >> 7;
    float acc[8];
#pragma unroll
    for (int r = 0; r < 8; ++r) acc[r] = 0.0f;

    for (int phase = 0; phase < 2; ++phase) {
        __syncthreads();  // xl ready (phase 0) / previous wl reads done (phase 1)
        for (int idx = t; idx < 64 * 128; idx += 256)
            wl[idx] = W[phase * 64 * 128 + idx];
        __syncthreads();
        for (int k2 = 0; k2 < 64; ++k2) {
            float wv = wl[k2 * 128 + col];         // consecutive cols: conflict-free
            int k = phase * 64 + k2;
#pragma unroll
            for (int r = 0; r < 8; ++r)            // xl read is wave-broadcast (free)
                acc[r] = fmaf(xl[(r * 2 + half) * 128 + k], wv, acc[r]);
        }
    }
#pragma unroll
    for (int r = 0; r < 8; ++r) {
        int node = base + r * 2 + half;
        if (node < n) Y[(size_t)node * 128 + col] = acc[r];
    }
}

// ---------------- sparse aggregation + bias + relu ----------------

__global__ __launch_bounds__(256) void k_aggregate(const float2* __restrict__ xw2,
                                                   const int* __restrict__ offs,
                                                   const int* __restrict__ csr_src,
                                                   const float* __restrict__ csr_norm,
                                                   const float* __restrict__ dinv,
                                                   const float* __restrict__ bias,
                                                   float* __restrict__ out, int n) {
    int lane = threadIdx.x & 63;
    int i = (blockIdx.x * 256 + threadIdx.x) >> 6;  // one wave per node
    if (i >= n) return;
    float di = dinv[i];
    float sn = di * di;                              // self-loop norm
    float2 v0 = xw2[(size_t)i * 64 + lane];
    float ax = v0.x * sn, ay = v0.y * sn;
    int beg = offs[i], fin = offs[i + 1];
    for (int j = beg; j < fin; ++j) {
        int s = csr_src[j];                          // wave-broadcast reads
        float w = csr_norm[j];
        float2 u = xw2[(size_t)s * 64 + lane];       // 512 B coalesced row gather
        ax = fmaf(u.x, w, ax);
        ay = fmaf(u.y, w, ay);
    }
    float bx = bias[lane * 2], by = bias[lane * 2 + 1];
    ax = fmaxf(ax + bx, 0.0f);
    ay = fmaxf(ay + by, 0.0f);
    ((float2*)out)[(size_t)i * 64 + lane] = make_float2(ax, ay);
}

// ---------------- launch ----------------

extern "C" void kernel_launch(void* const* d_in, const int* in_sizes, int n_in,
                              void* d_out, int out_size, void* d_ws, size_t ws_size,
                              hipStream_t stream) {
    const float* x  = (const float*)d_in[0];
    const int*   ei = (const int*)d_in[1];
    const float* W1 = (const float*)d_in[2];
    const float* b1 = (const float*)d_in[3];
    const float* W2 = (const float*)d_in[4];
    const float* b2 = (const float*)d_in[5];
    float* out = (float*)d_out;

    const int N = NNODES;
    const int E = in_sizes[1] / 2;  // 625000
    const int* src = ei;
    const int* dst = ei + E;
    const int NB = (N + 255) / 256;  // 196 scan blocks

    char* p = (char*)d_ws;
    size_t off = 0;
    auto take = [&](size_t bytes) -> void* {
        void* r = p + off;
        off = (off + bytes + 255) & ~(size_t)255;
        return r;
    };
    int*   cnt      = (int*)  take((size_t)N * 4);
    int*   offs     = (int*)  take((size_t)(N + 1) * 4);
    int*   cursor   = (int*)  take((size_t)N * 4);
    int*   bsum     = (int*)  take(256 * 4);
    float* dinv     = (float*)take((size_t)N * 4);
    int*   csr_src  = (int*)  take((size_t)E * 4);
    float* csr_norm = (float*)take((size_t)E * 4);
    float* xw       = (float*)take((size_t)N * 128 * 4);
    float* h        = (float*)take((size_t)N * 128 * 4);

    // graph preprocessing (shared by both layers)
    hipMemsetAsync(cnt, 0, (size_t)N * 4, stream);
    k_count<<<(E + 255) / 256, 256, 0, stream>>>(dst, cnt, E);
    k_dinv<<<(N + 255) / 256, 256, 0, stream>>>(cnt, dinv, N);
    k_scan1<<<NB, 256, 0, stream>>>(cnt, offs, bsum, N);
    k_scan2<<<1, 256, 0, stream>>>(bsum, NB);
    k_scan3<<<NB, 256, 0, stream>>>(offs, bsum, cursor, N, E);
    k_scatter<<<(E + 255) / 256, 256, 0, stream>>>(src, dst, dinv, cursor,
                                                   csr_src, csr_norm, E);

    // layer 1: h = relu(Ahat @ (x@W1) + b1)
    k_gemm128<<<(N + 15) / 16, 256, 0, stream>>>(x, W1, xw, N);
    k_aggregate<<<(N * 64 + 255) / 256, 256, 0, stream>>>(
        (const float2*)xw, offs, csr_src, csr_norm, dinv, b1, h, N);

    // layer 2: out = relu(Ahat @ (h@W2) + b2)
    k_gemm128<<<(N + 15) / 16, 256, 0, stream>>>(h, W2, xw, N);
    k_aggregate<<<(N * 64 + 255) / 256, 256, 0, stream>>>(
        (const float2*)xw, offs, csr_src, csr_norm, dinv, b2, out, N);
}

// Round 4
// 323.373 us; speedup vs baseline: 1.5747x; 1.2591x over previous
//
#include <hip/hip_runtime.h>
#include <hip/hip_bf16.h>

#define NNODES 50000

// ---------------- graph preprocessing ----------------

__global__ __launch_bounds__(256) void k_count(const int* __restrict__ dst,
                                               int* __restrict__ cnt, int E) {
    int e = blockIdx.x * 256 + threadIdx.x;
    if (e < E) atomicAdd(&cnt[dst[e]], 1);
}

__global__ __launch_bounds__(256) void k_dinv(const int* __restrict__ cnt,
                                              float* __restrict__ dinv, int N) {
    int i = blockIdx.x * 256 + threadIdx.x;
    if (i < N) dinv[i] = rsqrtf((float)cnt[i] + 1.0f);  // +1 self-loop; deg>=1 always
}

// ---- hierarchical exclusive scan of cnt[N] -> offs[N+1] (3 kernels) ----

__global__ __launch_bounds__(256) void k_scan1(const int* __restrict__ cnt,
                                               int* __restrict__ offs,
                                               int* __restrict__ bsum, int N) {
    __shared__ int sh[256];
    int t = threadIdx.x;
    int i = blockIdx.x * 256 + t;
    int v = (i < N) ? cnt[i] : 0;
    sh[t] = v;
    __syncthreads();
#pragma unroll
    for (int o = 1; o < 256; o <<= 1) {
        int u = (t >= o) ? sh[t - o] : 0;
        __syncthreads();
        sh[t] += u;
        __syncthreads();
    }
    if (i < N) offs[i] = sh[t] - v;  // local exclusive
    if (t == 255) bsum[blockIdx.x] = sh[255];
}

__global__ __launch_bounds__(256) void k_scan2(int* __restrict__ bsum, int NB) {
    __shared__ int sh[256];
    int t = threadIdx.x;
    int v = (t < NB) ? bsum[t] : 0;
    sh[t] = v;
    __syncthreads();
#pragma unroll
    for (int o = 1; o < 256; o <<= 1) {
        int u = (t >= o) ? sh[t - o] : 0;
        __syncthreads();
        sh[t] += u;
        __syncthreads();
    }
    if (t < NB) bsum[t] = sh[t] - v;  // exclusive
}

__global__ __launch_bounds__(256) void k_scan3(int* __restrict__ offs,
                                               const int* __restrict__ bsum,
                                               int* __restrict__ cursor, int N, int E) {
    int i = blockIdx.x * 256 + threadIdx.x;
    if (i < N) {
        int o = offs[i] + bsum[blockIdx.x];
        offs[i] = o;
        cursor[i] = o;
    }
    if (i == 0) offs[N] = E;
}

__global__ __launch_bounds__(256) void k_scatter(const int* __restrict__ src,
                                                 const int* __restrict__ dst,
                                                 const float* __restrict__ dinv,
                                                 int* __restrict__ cursor,
                                                 int* __restrict__ csr_src,
                                                 float* __restrict__ csr_norm, int E) {
    int e = blockIdx.x * 256 + threadIdx.x;
    if (e >= E) return;
    int s = src[e], d = dst[e];
    int pos = atomicAdd(&cursor[d], 1);
    csr_src[pos] = s;
    csr_norm[pos] = dinv[s] * dinv[d];
}

// ------- dense: Yb[n,128](bf16) = X[n,128](f32) @ W[128,128](f32), fp32 accum -------

__global__ __launch_bounds__(256) void k_gemm128(const float* __restrict__ X,
                                                 const float* __restrict__ W,
                                                 __hip_bfloat16* __restrict__ Yb, int n) {
    __shared__ float wl[64 * 128];  // 32 KB: half of W
    __shared__ float xl[16 * 128];  // 8 KB: 16-node x tile
    int t = threadIdx.x;
    int base = blockIdx.x * 16;
    for (int idx = t; idx < 16 * 128; idx += 256) {
        int node = base + (idx >> 7);
        xl[idx] = (node < n) ? X[(size_t)node * 128 + (idx & 127)] : 0.0f;
    }
    int col = t & 127;
    int half = t >> 7;
    float acc[8];
#pragma unroll
    for (int r = 0; r < 8; ++r) acc[r] = 0.0f;

    for (int phase = 0; phase < 2; ++phase) {
        __syncthreads();
        for (int idx = t; idx < 64 * 128; idx += 256)
            wl[idx] = W[phase * 64 * 128 + idx];
        __syncthreads();
        for (int k2 = 0; k2 < 64; ++k2) {
            float wv = wl[k2 * 128 + col];         // consecutive cols: conflict-free
            int k = phase * 64 + k2;
#pragma unroll
            for (int r = 0; r < 8; ++r)            // xl read is wave-broadcast
                acc[r] = fmaf(xl[(r * 2 + half) * 128 + k], wv, acc[r]);
        }
    }
#pragma unroll
    for (int r = 0; r < 8; ++r) {
        int node = base + r * 2 + half;
        if (node < n) Yb[(size_t)node * 128 + col] = __float2bfloat16(acc[r]);
    }
}

// ---------------- sparse aggregation + bias + relu (bf16 gather) ----------------

__device__ __forceinline__ float bf_lo(unsigned int u) {
    return __uint_as_float(u << 16);
}
__device__ __forceinline__ float bf_hi(unsigned int u) {
    return __uint_as_float(u & 0xffff0000u);
}

__global__ __launch_bounds__(256) void k_aggregate(const unsigned int* __restrict__ xwb,
                                                   const int* __restrict__ offs,
                                                   const int* __restrict__ csr_src,
                                                   const float* __restrict__ csr_norm,
                                                   const float* __restrict__ dinv,
                                                   const float* __restrict__ bias,
                                                   float* __restrict__ out, int n) {
    int lane = threadIdx.x & 63;
    int i = (blockIdx.x * 256 + threadIdx.x) >> 6;  // one wave per node
    if (i >= n) return;
    float di = dinv[i];
    float sn = di * di;                              // self-loop norm
    unsigned int v0 = xwb[(size_t)i * 64 + lane];    // 2 bf16 per lane (256 B row)
    float ax = bf_lo(v0) * sn, ay = bf_hi(v0) * sn;
    float bx2 = 0.0f, by2 = 0.0f;                    // second accumulator pair
    int beg = offs[i], fin = offs[i + 1];
    int j = beg;
    for (; j + 4 <= fin; j += 4) {                   // 4 gathers in flight
        int s0 = csr_src[j], s1 = csr_src[j + 1];
        int s2 = csr_src[j + 2], s3 = csr_src[j + 3];
        float w0 = csr_norm[j], w1 = csr_norm[j + 1];
        float w2 = csr_norm[j + 2], w3 = csr_norm[j + 3];
        unsigned int u0 = xwb[(size_t)s0 * 64 + lane];
        unsigned int u1 = xwb[(size_t)s1 * 64 + lane];
        unsigned int u2 = xwb[(size_t)s2 * 64 + lane];
        unsigned int u3 = xwb[(size_t)s3 * 64 + lane];
        ax = fmaf(bf_lo(u0), w0, ax);  ay = fmaf(bf_hi(u0), w0, ay);
        bx2 = fmaf(bf_lo(u1), w1, bx2); by2 = fmaf(bf_hi(u1), w1, by2);
        ax = fmaf(bf_lo(u2), w2, ax);  ay = fmaf(bf_hi(u2), w2, ay);
        bx2 = fmaf(bf_lo(u3), w3, bx2); by2 = fmaf(bf_hi(u3), w3, by2);
    }
    for (; j < fin; ++j) {
        int s = csr_src[j];
        float w = csr_norm[j];
        unsigned int u = xwb[(size_t)s * 64 + lane];
        ax = fmaf(bf_lo(u), w, ax);
        ay = fmaf(bf_hi(u), w, ay);
    }
    ax += bx2;
    ay += by2;
    float bx = bias[lane * 2], by = bias[lane * 2 + 1];
    ax = fmaxf(ax + bx, 0.0f);
    ay = fmaxf(ay + by, 0.0f);
    ((float2*)out)[(size_t)i * 64 + lane] = make_float2(ax, ay);
}

// ---------------- launch ----------------

extern "C" void kernel_launch(void* const* d_in, const int* in_sizes, int n_in,
                              void* d_out, int out_size, void* d_ws, size_t ws_size,
                              hipStream_t stream) {
    const float* x  = (const float*)d_in[0];
    const int*   ei = (const int*)d_in[1];
    const float* W1 = (const float*)d_in[2];
    const float* b1 = (const float*)d_in[3];
    const float* W2 = (const float*)d_in[4];
    const float* b2 = (const float*)d_in[5];
    float* out = (float*)d_out;

    const int N = NNODES;
    const int E = in_sizes[1] / 2;  // 625000
    const int* src = ei;
    const int* dst = ei + E;
    const int NB = (N + 255) / 256;  // 196 scan blocks

    char* p = (char*)d_ws;
    size_t off = 0;
    auto take = [&](size_t bytes) -> void* {
        void* r = p + off;
        off = (off + bytes + 255) & ~(size_t)255;
        return r;
    };
    int*   cnt      = (int*)  take((size_t)N * 4);
    int*   offs     = (int*)  take((size_t)(N + 1) * 4);
    int*   cursor   = (int*)  take((size_t)N * 4);
    int*   bsum     = (int*)  take(256 * 4);
    float* dinv     = (float*)take((size_t)N * 4);
    int*   csr_src  = (int*)  take((size_t)E * 4);
    float* csr_norm = (float*)take((size_t)E * 4);
    __hip_bfloat16* xwb = (__hip_bfloat16*)take((size_t)N * 128 * 2);  // bf16 gather buffer
    float* h        = (float*)take((size_t)N * 128 * 4);

    // graph preprocessing (shared by both layers)
    hipMemsetAsync(cnt, 0, (size_t)N * 4, stream);
    k_count<<<(E + 255) / 256, 256, 0, stream>>>(dst, cnt, E);
    k_dinv<<<(N + 255) / 256, 256, 0, stream>>>(cnt, dinv, N);
    k_scan1<<<NB, 256, 0, stream>>>(cnt, offs, bsum, N);
    k_scan2<<<1, 256, 0, stream>>>(bsum, NB);
    k_scan3<<<NB, 256, 0, stream>>>(offs, bsum, cursor, N, E);
    k_scatter<<<(E + 255) / 256, 256, 0, stream>>>(src, dst, dinv, cursor,
                                                   csr_src, csr_norm, E);

    // layer 1: h = relu(Ahat @ (x@W1) + b1)
    k_gemm128<<<(N + 15) / 16, 256, 0, stream>>>(x, W1, xwb, N);
    k_aggregate<<<(N * 64 + 255) / 256, 256, 0, stream>>>(
        (const unsigned int*)xwb, offs, csr_src, csr_norm, dinv, b1, h, N);

    // layer 2: out = relu(Ahat @ (h@W2) + b2)
    k_gemm128<<<(N + 15) / 16, 256, 0, stream>>>(h, W2, xwb, N);
    k_aggregate<<<(N * 64 + 255) / 256, 256, 0, stream>>>(
        (const unsigned int*)xwb, offs, csr_src, csr_norm, dinv, b2, out, N);
}

// Round 5
// 260.743 us; speedup vs baseline: 1.9530x; 1.2402x over previous
//
#include <hip/hip_runtime.h>
#include <hip/hip_bf16.h>

#define NNODES 50000

typedef short bf16x8 __attribute__((ext_vector_type(8)));
typedef float f32x4 __attribute__((ext_vector_type(4)));

__device__ __forceinline__ unsigned short f2bf_rn(float f) {
    unsigned int u = __float_as_uint(f);
    return (unsigned short)((u + 0x7fffu + ((u >> 16) & 1u)) >> 16);
}
__device__ __forceinline__ float bf2f(unsigned short s) {
    return __uint_as_float(((unsigned int)s) << 16);
}

// ---------------- graph preprocessing ----------------

__global__ __launch_bounds__(256) void k_count(const int* __restrict__ dst,
                                               int* __restrict__ cnt, int E) {
    int e = blockIdx.x * 256 + threadIdx.x;
    if (e < E) atomicAdd(&cnt[dst[e]], 1);
}

__global__ __launch_bounds__(256) void k_dinv(const int* __restrict__ cnt,
                                              float* __restrict__ dinv, int N) {
    int i = blockIdx.x * 256 + threadIdx.x;
    if (i < N) dinv[i] = rsqrtf((float)cnt[i] + 1.0f);  // +1 self-loop
}

// ---- hierarchical exclusive scan of cnt[N] -> offs[N+1] ----

__global__ __launch_bounds__(256) void k_scan1(const int* __restrict__ cnt,
                                               int* __restrict__ offs,
                                               int* __restrict__ bsum, int N) {
    __shared__ int sh[256];
    int t = threadIdx.x;
    int i = blockIdx.x * 256 + t;
    int v = (i < N) ? cnt[i] : 0;
    sh[t] = v;
    __syncthreads();
#pragma unroll
    for (int o = 1; o < 256; o <<= 1) {
        int u = (t >= o) ? sh[t - o] : 0;
        __syncthreads();
        sh[t] += u;
        __syncthreads();
    }
    if (i < N) offs[i] = sh[t] - v;
    if (t == 255) bsum[blockIdx.x] = sh[255];
}

__global__ __launch_bounds__(256) void k_scan2(int* __restrict__ bsum, int NB) {
    __shared__ int sh[256];
    int t = threadIdx.x;
    int v = (t < NB) ? bsum[t] : 0;
    sh[t] = v;
    __syncthreads();
#pragma unroll
    for (int o = 1; o < 256; o <<= 1) {
        int u = (t >= o) ? sh[t - o] : 0;
        __syncthreads();
        sh[t] += u;
        __syncthreads();
    }
    if (t < NB) bsum[t] = sh[t] - v;
}

__global__ __launch_bounds__(256) void k_scan3(int* __restrict__ offs,
                                               const int* __restrict__ bsum,
                                               int* __restrict__ cursor, int N, int E) {
    int i = blockIdx.x * 256 + threadIdx.x;
    if (i < N) {
        int o = offs[i] + bsum[blockIdx.x];
        offs[i] = o;
        cursor[i] = o;
    }
    if (i == 0) offs[N] = E;
}

__global__ __launch_bounds__(256) void k_scatter(const int* __restrict__ src,
                                                 const int* __restrict__ dst,
                                                 const float* __restrict__ dinv,
                                                 int* __restrict__ cursor,
                                                 int* __restrict__ csr_src,
                                                 float* __restrict__ csr_norm, int E) {
    int e = blockIdx.x * 256 + threadIdx.x;
    if (e >= E) return;
    int s = src[e], d = dst[e];
    int pos = atomicAdd(&cursor[d], 1);
    csr_src[pos] = s;
    csr_norm[pos] = dinv[s] * dinv[d];
}

// ---- one-time: WT[c][k] (bf16) = W[k][c] (f32), 128x128, one block ----

__global__ __launch_bounds__(256) void k_wt(const float* __restrict__ W,
                                            unsigned short* __restrict__ WT) {
    __shared__ float tile[128 * 129];  // +1 pad: conflict-free column reads
    int t = threadIdx.x;
    for (int idx = t; idx < 128 * 128; idx += 256)
        tile[(idx >> 7) * 129 + (idx & 127)] = W[idx];
    __syncthreads();
    for (int idx = t; idx < 128 * 128; idx += 256) {
        int c = idx >> 7, k = idx & 127;
        WT[c * 128 + k] = f2bf_rn(tile[k * 129 + c]);
    }
}

// ---- dense MFMA: Yb[n,128](bf16) = X[n,128](f32) @ W, split hi/lo A ----
// Per block: 64 nodes x 128 cols, 4 waves. mfma_f32_16x16x32_bf16.
// A layout: A[m=lane&15][k=quad*8+j]; B: B[k=quad*8+j][n=lane&15];
// C: col=lane&15, row=quad*4+reg (m89/m120-verified mappings).

#define LP 136  // padded LDS row (272 B = 16*17: aligned b128, staggered banks)

__global__ __launch_bounds__(256) void k_gemm_mfma(const float* __restrict__ X,
                                                   const unsigned short* __restrict__ WT,
                                                   unsigned short* __restrict__ Yb, int n) {
    __shared__ unsigned short Wl[128 * LP];  // 34 KB
    __shared__ unsigned short Ah[64 * LP];   // 17 KB
    __shared__ unsigned short Al[64 * LP];   // 17 KB
    int t = threadIdx.x;
    int base = blockIdx.x * 64;

    // stage WT rows (bf16, coalesced 16 B)
    for (int idx = t; idx < 128 * 16; idx += 256) {
        int r = idx >> 4, c8 = (idx & 15) << 3;
        *(uint4*)&Wl[r * LP + c8] = *(const uint4*)&WT[r * 128 + c8];
    }
    // stage X tile as hi/lo bf16 (coalesced float4 reads, b64 LDS writes)
    for (int idx = t; idx < 64 * 32; idx += 256) {
        int node = idx >> 5, c4 = (idx & 31) << 2;
        float4 v = make_float4(0.f, 0.f, 0.f, 0.f);
        if (base + node < n) v = *(const float4*)&X[(size_t)(base + node) * 128 + c4];
        unsigned short h0 = f2bf_rn(v.x), h1 = f2bf_rn(v.y);
        unsigned short h2 = f2bf_rn(v.z), h3 = f2bf_rn(v.w);
        unsigned short l0 = f2bf_rn(v.x - bf2f(h0)), l1 = f2bf_rn(v.y - bf2f(h1));
        unsigned short l2 = f2bf_rn(v.z - bf2f(h2)), l3 = f2bf_rn(v.w - bf2f(h3));
        uint2 hp, lp;
        hp.x = (unsigned)h0 | ((unsigned)h1 << 16);
        hp.y = (unsigned)h2 | ((unsigned)h3 << 16);
        lp.x = (unsigned)l0 | ((unsigned)l1 << 16);
        lp.y = (unsigned)l2 | ((unsigned)l3 << 16);
        *(uint2*)&Ah[node * LP + c4] = hp;
        *(uint2*)&Al[node * LP + c4] = lp;
    }
    __syncthreads();

    int lane = t & 63;
    int w = t >> 6;
    int m = lane & 15;
    int quad = lane >> 4;

    f32x4 acc[8];
#pragma unroll
    for (int i = 0; i < 8; ++i) acc[i] = f32x4{0.f, 0.f, 0.f, 0.f};

    int arow = (w * 16 + m) * LP;
#pragma unroll
    for (int kt = 0; kt < 4; ++kt) {
        int ko = kt * 32 + quad * 8;
        bf16x8 ah = *(const bf16x8*)&Ah[arow + ko];
        bf16x8 al = *(const bf16x8*)&Al[arow + ko];
#pragma unroll
        for (int ct = 0; ct < 8; ++ct) {
            bf16x8 b = *(const bf16x8*)&Wl[(ct * 16 + m) * LP + ko];
            acc[ct] = __builtin_amdgcn_mfma_f32_16x16x32_bf16(ah, b, acc[ct], 0, 0, 0);
            acc[ct] = __builtin_amdgcn_mfma_f32_16x16x32_bf16(al, b, acc[ct], 0, 0, 0);
        }
    }

#pragma unroll
    for (int ct = 0; ct < 8; ++ct) {
#pragma unroll
        for (int r = 0; r < 4; ++r) {
            int node = base + w * 16 + quad * 4 + r;
            if (node < n) Yb[(size_t)node * 128 + ct * 16 + m] = f2bf_rn(acc[ct][r]);
        }
    }
}

// ---------------- sparse aggregation + bias + relu (bf16 gather) ----------------

__device__ __forceinline__ float bf_lo(unsigned int u) { return __uint_as_float(u << 16); }
__device__ __forceinline__ float bf_hi(unsigned int u) { return __uint_as_float(u & 0xffff0000u); }

__global__ __launch_bounds__(256) void k_aggregate(const unsigned int* __restrict__ xwb,
                                                   const int* __restrict__ offs,
                                                   const int* __restrict__ csr_src,
                                                   const float* __restrict__ csr_norm,
                                                   const float* __restrict__ dinv,
                                                   const float* __restrict__ bias,
                                                   float* __restrict__ out, int n) {
    int lane = threadIdx.x & 63;
    int i = (blockIdx.x * 256 + threadIdx.x) >> 6;  // one wave per node
    if (i >= n) return;
    float di = dinv[i];
    float sn = di * di;
    unsigned int v0 = xwb[(size_t)i * 64 + lane];
    float ax = bf_lo(v0) * sn, ay = bf_hi(v0) * sn;
    float bx2 = 0.0f, by2 = 0.0f;
    int beg = offs[i], fin = offs[i + 1];
    int j = beg;
    for (; j + 4 <= fin; j += 4) {
        int s0 = csr_src[j], s1 = csr_src[j + 1];
        int s2 = csr_src[j + 2], s3 = csr_src[j + 3];
        float w0 = csr_norm[j], w1 = csr_norm[j + 1];
        float w2 = csr_norm[j + 2], w3 = csr_norm[j + 3];
        unsigned int u0 = xwb[(size_t)s0 * 64 + lane];
        unsigned int u1 = xwb[(size_t)s1 * 64 + lane];
        unsigned int u2 = xwb[(size_t)s2 * 64 + lane];
        unsigned int u3 = xwb[(size_t)s3 * 64 + lane];
        ax = fmaf(bf_lo(u0), w0, ax);  ay = fmaf(bf_hi(u0), w0, ay);
        bx2 = fmaf(bf_lo(u1), w1, bx2); by2 = fmaf(bf_hi(u1), w1, by2);
        ax = fmaf(bf_lo(u2), w2, ax);  ay = fmaf(bf_hi(u2), w2, ay);
        bx2 = fmaf(bf_lo(u3), w3, bx2); by2 = fmaf(bf_hi(u3), w3, by2);
    }
    for (; j < fin; ++j) {
        int s = csr_src[j];
        float w = csr_norm[j];
        unsigned int u = xwb[(size_t)s * 64 + lane];
        ax = fmaf(bf_lo(u), w, ax);
        ay = fmaf(bf_hi(u), w, ay);
    }
    ax += bx2;
    ay += by2;
    float bx = bias[lane * 2], by = bias[lane * 2 + 1];
    ax = fmaxf(ax + bx, 0.0f);
    ay = fmaxf(ay + by, 0.0f);
    ((float2*)out)[(size_t)i * 64 + lane] = make_float2(ax, ay);
}

// ---------------- launch ----------------

extern "C" void kernel_launch(void* const* d_in, const int* in_sizes, int n_in,
                              void* d_out, int out_size, void* d_ws, size_t ws_size,
                              hipStream_t stream) {
    const float* x  = (const float*)d_in[0];
    const int*   ei = (const int*)d_in[1];
    const float* W1 = (const float*)d_in[2];
    const float* b1 = (const float*)d_in[3];
    const float* W2 = (const float*)d_in[4];
    const float* b2 = (const float*)d_in[5];
    float* out = (float*)d_out;

    const int N = NNODES;
    const int E = in_sizes[1] / 2;  // 625000
    const int* src = ei;
    const int* dst = ei + E;
    const int NB = (N + 255) / 256;

    char* p = (char*)d_ws;
    size_t off = 0;
    auto take = [&](size_t bytes) -> void* {
        void* r = p + off;
        off = (off + bytes + 255) & ~(size_t)255;
        return r;
    };
    int*   cnt      = (int*)  take((size_t)N * 4);
    int*   offs     = (int*)  take((size_t)(N + 1) * 4);
    int*   cursor   = (int*)  take((size_t)N * 4);
    int*   bsum     = (int*)  take(256 * 4);
    float* dinv     = (float*)take((size_t)N * 4);
    int*   csr_src  = (int*)  take((size_t)E * 4);
    float* csr_norm = (float*)take((size_t)E * 4);
    unsigned short* w1t = (unsigned short*)take(128 * 128 * 2);
    unsigned short* w2t = (unsigned short*)take(128 * 128 * 2);
    unsigned short* xwb = (unsigned short*)take((size_t)N * 128 * 2);
    float* h        = (float*)take((size_t)N * 128 * 4);

    // one-time weight transposes (bf16)
    k_wt<<<1, 256, 0, stream>>>(W1, w1t);
    k_wt<<<1, 256, 0, stream>>>(W2, w2t);

    // graph preprocessing (shared by both layers)
    hipMemsetAsync(cnt, 0, (size_t)N * 4, stream);
    k_count<<<(E + 255) / 256, 256, 0, stream>>>(dst, cnt, E);
    k_dinv<<<(N + 255) / 256, 256, 0, stream>>>(cnt, dinv, N);
    k_scan1<<<NB, 256, 0, stream>>>(cnt, offs, bsum, N);
    k_scan2<<<1, 256, 0, stream>>>(bsum, NB);
    k_scan3<<<NB, 256, 0, stream>>>(offs, bsum, cursor, N, E);
    k_scatter<<<(E + 255) / 256, 256, 0, stream>>>(src, dst, dinv, cursor,
                                                   csr_src, csr_norm, E);

    const int GB = (N + 63) / 64;  // 782 GEMM blocks

    // layer 1: h = relu(Ahat @ (x@W1) + b1)
    k_gemm_mfma<<<GB, 256, 0, stream>>>(x, w1t, xwb, N);
    k_aggregate<<<(N * 64 + 255) / 256, 256, 0, stream>>>(
        (const unsigned int*)xwb, offs, csr_src, csr_norm, dinv, b1, h, N);

    // layer 2: out = relu(Ahat @ (h@W2) + b2)
    k_gemm_mfma<<<GB, 256, 0, stream>>>(h, w2t, xwb, N);
    k_aggregate<<<(N * 64 + 255) / 256, 256, 0, stream>>>(
        (const unsigned int*)xwb, offs, csr_src, csr_norm, dinv, b2, out, N);
}

// Round 6
// 253.530 us; speedup vs baseline: 2.0085x; 1.0284x over previous
//
#include <hip/hip_runtime.h>
#include <hip/hip_bf16.h>

#define NNODES 50000

typedef short bf16x8 __attribute__((ext_vector_type(8)));
typedef float f32x4 __attribute__((ext_vector_type(4)));

__device__ __forceinline__ unsigned short f2bf_rn(float f) {
    unsigned int u = __float_as_uint(f);
    return (unsigned short)((u + 0x7fffu + ((u >> 16) & 1u)) >> 16);
}

// ---------------- graph preprocessing ----------------

__global__ __launch_bounds__(256) void k_count(const int* __restrict__ dst,
                                               int* __restrict__ cnt, int E) {
    int e = blockIdx.x * 256 + threadIdx.x;
    if (e < E) atomicAdd(&cnt[dst[e]], 1);
}

// per-block exclusive scan of cnt; block totals; fused dinv = rsqrt(cnt+1)
__global__ __launch_bounds__(256) void k_scan1(const int* __restrict__ cnt,
                                               int* __restrict__ offs,
                                               int* __restrict__ bsum,
                                               float* __restrict__ dinv, int N) {
    __shared__ int sh[256];
    int t = threadIdx.x;
    int i = blockIdx.x * 256 + t;
    int v = (i < N) ? cnt[i] : 0;
    if (i < N) dinv[i] = rsqrtf((float)v + 1.0f);  // +1 self-loop
    sh[t] = v;
    __syncthreads();
#pragma unroll
    for (int o = 1; o < 256; o <<= 1) {
        int u = (t >= o) ? sh[t - o] : 0;
        __syncthreads();
        sh[t] += u;
        __syncthreads();
    }
    if (i < N) offs[i] = sh[t] - v;
    if (t == 255) bsum[blockIdx.x] = sh[255];
}

__global__ __launch_bounds__(256) void k_scan2(int* __restrict__ bsum, int NB) {
    __shared__ int sh[256];
    int t = threadIdx.x;
    int v = (t < NB) ? bsum[t] : 0;
    sh[t] = v;
    __syncthreads();
#pragma unroll
    for (int o = 1; o < 256; o <<= 1) {
        int u = (t >= o) ? sh[t - o] : 0;
        __syncthreads();
        sh[t] += u;
        __syncthreads();
    }
    if (t < NB) bsum[t] = sh[t] - v;
}

__global__ __launch_bounds__(256) void k_scan3(int* __restrict__ offs,
                                               const int* __restrict__ bsum,
                                               int* __restrict__ cursor, int N, int E) {
    int i = blockIdx.x * 256 + threadIdx.x;
    if (i < N) {
        int o = offs[i] + bsum[blockIdx.x];
        offs[i] = o;
        cursor[i] = o;
    }
    if (i == 0) offs[N] = E;
}

// CSR scatter: only src index (norm factored out of the sum)
__global__ __launch_bounds__(256) void k_scatter(const int* __restrict__ src,
                                                 const int* __restrict__ dst,
                                                 int* __restrict__ cursor,
                                                 int* __restrict__ csr_src, int E) {
    int e = blockIdx.x * 256 + threadIdx.x;
    if (e >= E) return;
    int s = src[e], d = dst[e];
    int pos = atomicAdd(&cursor[d], 1);
    csr_src[pos] = s;
}

// ---- one-time: WT[c][k] (bf16) = W[k][c] (f32), both weights, 2 blocks ----

__global__ __launch_bounds__(256) void k_wt(const float* __restrict__ W1,
                                            const float* __restrict__ W2,
                                            unsigned short* __restrict__ WT1,
                                            unsigned short* __restrict__ WT2) {
    const float* W = blockIdx.x ? W2 : W1;
    unsigned short* WT = blockIdx.x ? WT2 : WT1;
    __shared__ float tile[128 * 129];  // +1 pad: conflict-free column reads
    int t = threadIdx.x;
    for (int idx = t; idx < 128 * 128; idx += 256)
        tile[(idx >> 7) * 129 + (idx & 127)] = W[idx];
    __syncthreads();
    for (int idx = t; idx < 128 * 128; idx += 256) {
        int c = idx >> 7, k = idx & 127;
        WT[c * 128 + k] = f2bf_rn(tile[k * 129 + c]);
    }
}

// ---- dense MFMA: Yb[n,128](bf16) = X[n,128](f32, bf16-rounded) @ W ----
// Per block: 64 nodes x 128 cols, 4 waves. mfma_f32_16x16x32_bf16.
// A[m=lane&15][k=quad*8+j]; B[k=quad*8+j][n=lane&15]; C col=lane&15,row=quad*4+reg.

#define LP 136  // padded LDS row (272 B): aligned b128, staggered banks

__global__ __launch_bounds__(256) void k_gemm_mfma(const float* __restrict__ X,
                                                   const unsigned short* __restrict__ WT,
                                                   unsigned short* __restrict__ Yb, int n) {
    __shared__ unsigned short Wl[128 * LP];  // 34 KB
    __shared__ unsigned short Ah[64 * LP];   // 17 KB
    int t = threadIdx.x;
    int base = blockIdx.x * 64;

    // stage WT rows (bf16, coalesced 16 B)
    for (int idx = t; idx < 128 * 16; idx += 256) {
        int r = idx >> 4, c8 = (idx & 15) << 3;
        *(uint4*)&Wl[r * LP + c8] = *(const uint4*)&WT[r * 128 + c8];
    }
    // stage X tile as bf16 (coalesced float4 reads, b64 LDS writes)
    for (int idx = t; idx < 64 * 32; idx += 256) {
        int node = idx >> 5, c4 = (idx & 31) << 2;
        float4 v = make_float4(0.f, 0.f, 0.f, 0.f);
        if (base + node < n) v = *(const float4*)&X[(size_t)(base + node) * 128 + c4];
        uint2 hp;
        hp.x = (unsigned)f2bf_rn(v.x) | ((unsigned)f2bf_rn(v.y) << 16);
        hp.y = (unsigned)f2bf_rn(v.z) | ((unsigned)f2bf_rn(v.w) << 16);
        *(uint2*)&Ah[node * LP + c4] = hp;
    }
    __syncthreads();

    int lane = t & 63;
    int w = t >> 6;
    int m = lane & 15;
    int quad = lane >> 4;

    f32x4 acc[8];
#pragma unroll
    for (int i = 0; i < 8; ++i) acc[i] = f32x4{0.f, 0.f, 0.f, 0.f};

    int arow = (w * 16 + m) * LP;
#pragma unroll
    for (int kt = 0; kt < 4; ++kt) {
        int ko = kt * 32 + quad * 8;
        bf16x8 ah = *(const bf16x8*)&Ah[arow + ko];
#pragma unroll
        for (int ct = 0; ct < 8; ++ct) {
            bf16x8 b = *(const bf16x8*)&Wl[(ct * 16 + m) * LP + ko];
            acc[ct] = __builtin_amdgcn_mfma_f32_16x16x32_bf16(ah, b, acc[ct], 0, 0, 0);
        }
    }

#pragma unroll
    for (int ct = 0; ct < 8; ++ct) {
#pragma unroll
        for (int r = 0; r < 4; ++r) {
            int node = base + w * 16 + quad * 4 + r;
            if (node < n) Yb[(size_t)node * 128 + ct * 16 + m] = f2bf_rn(acc[ct][r]);
        }
    }
}

// ---------------- sparse aggregation + bias + relu (bf16 gather) ----------------
// out_i = di * ( sum_j dinv[s_j]*x_{s_j}  +  di*x_i ) + b ; di = dinv[i]

__device__ __forceinline__ float bf_lo(unsigned int u) { return __uint_as_float(u << 16); }
__device__ __forceinline__ float bf_hi(unsigned int u) { return __uint_as_float(u & 0xffff0000u); }

__global__ __launch_bounds__(256) void k_aggregate(const unsigned int* __restrict__ xwb,
                                                   const int* __restrict__ offs,
                                                   const int* __restrict__ csr_src,
                                                   const float* __restrict__ dinv,
                                                   const float* __restrict__ bias,
                                                   float* __restrict__ out, int n) {
    int lane = threadIdx.x & 63;
    int i = (blockIdx.x * 256 + threadIdx.x) >> 6;  // one wave per node
    if (i >= n) return;
    float di = dinv[i];
    unsigned int v0 = xwb[(size_t)i * 64 + lane];
    float ax = di * bf_lo(v0), ay = di * bf_hi(v0);  // self term (di*x_i)
    float bx2 = 0.0f, by2 = 0.0f;
    int beg = offs[i], fin = offs[i + 1];
    int j = beg;
    for (; j + 4 <= fin; j += 4) {
        int s0 = csr_src[j], s1 = csr_src[j + 1];
        int s2 = csr_src[j + 2], s3 = csr_src[j + 3];
        float w0 = dinv[s0], w1 = dinv[s1];          // wave-broadcast loads
        float w2 = dinv[s2], w3 = dinv[s3];
        unsigned int u0 = xwb[(size_t)s0 * 64 + lane];
        unsigned int u1 = xwb[(size_t)s1 * 64 + lane];
        unsigned int u2 = xwb[(size_t)s2 * 64 + lane];
        unsigned int u3 = xwb[(size_t)s3 * 64 + lane];
        ax = fmaf(bf_lo(u0), w0, ax);  ay = fmaf(bf_hi(u0), w0, ay);
        bx2 = fmaf(bf_lo(u1), w1, bx2); by2 = fmaf(bf_hi(u1), w1, by2);
        ax = fmaf(bf_lo(u2), w2, ax);  ay = fmaf(bf_hi(u2), w2, ay);
        bx2 = fmaf(bf_lo(u3), w3, bx2); by2 = fmaf(bf_hi(u3), w3, by2);
    }
    for (; j < fin; ++j) {
        int s = csr_src[j];
        float w = dinv[s];
        unsigned int u = xwb[(size_t)s * 64 + lane];
        ax = fmaf(bf_lo(u), w, ax);
        ay = fmaf(bf_hi(u), w, ay);
    }
    ax += bx2;
    ay += by2;
    float bx = bias[lane * 2], by = bias[lane * 2 + 1];
    ax = fmaxf(fmaf(di, ax, bx), 0.0f);
    ay = fmaxf(fmaf(di, ay, by), 0.0f);
    ((float2*)out)[(size_t)i * 64 + lane] = make_float2(ax, ay);
}

// ---------------- launch ----------------

extern "C" void kernel_launch(void* const* d_in, const int* in_sizes, int n_in,
                              void* d_out, int out_size, void* d_ws, size_t ws_size,
                              hipStream_t stream) {
    const float* x  = (const float*)d_in[0];
    const int*   ei = (const int*)d_in[1];
    const float* W1 = (const float*)d_in[2];
    const float* b1 = (const float*)d_in[3];
    const float* W2 = (const float*)d_in[4];
    const float* b2 = (const float*)d_in[5];
    float* out = (float*)d_out;

    const int N = NNODES;
    const int E = in_sizes[1] / 2;  // 625000
    const int* src = ei;
    const int* dst = ei + E;
    const int NB = (N + 255) / 256;

    char* p = (char*)d_ws;
    size_t off = 0;
    auto take = [&](size_t bytes) -> void* {
        void* r = p + off;
        off = (off + bytes + 255) & ~(size_t)255;
        return r;
    };
    int*   cnt     = (int*)  take((size_t)N * 4);
    int*   offs    = (int*)  take((size_t)(N + 1) * 4);
    int*   cursor  = (int*)  take((size_t)N * 4);
    int*   bsum    = (int*)  take(256 * 4);
    float* dinv    = (float*)take((size_t)N * 4);
    int*   csr_src = (int*)  take((size_t)E * 4);
    unsigned short* w1t = (unsigned short*)take(128 * 128 * 2);
    unsigned short* w2t = (unsigned short*)take(128 * 128 * 2);
    unsigned short* xwb = (unsigned short*)take((size_t)N * 128 * 2);
    float* h       = (float*)take((size_t)N * 128 * 4);

    // one-time weight transposes (bf16), both in one launch
    k_wt<<<2, 256, 0, stream>>>(W1, W2, w1t, w2t);

    // graph preprocessing (shared by both layers)
    hipMemsetAsync(cnt, 0, (size_t)N * 4, stream);
    k_count<<<(E + 255) / 256, 256, 0, stream>>>(dst, cnt, E);
    k_scan1<<<NB, 256, 0, stream>>>(cnt, offs, bsum, dinv, N);
    k_scan2<<<1, 256, 0, stream>>>(bsum, NB);
    k_scan3<<<NB, 256, 0, stream>>>(offs, bsum, cursor, N, E);
    k_scatter<<<(E + 255) / 256, 256, 0, stream>>>(src, dst, cursor, csr_src, E);

    const int GB = (N + 63) / 64;  // 782 GEMM blocks

    // layer 1: h = relu(Ahat @ (x@W1) + b1)
    k_gemm_mfma<<<GB, 256, 0, stream>>>(x, w1t, xwb, N);
    k_aggregate<<<(N * 64 + 255) / 256, 256, 0, stream>>>(
        (const unsigned int*)xwb, offs, csr_src, dinv, b1, h, N);

    // layer 2: out = relu(Ahat @ (h@W2) + b2)
    k_gemm_mfma<<<GB, 256, 0, stream>>>(h, w2t, xwb, N);
    k_aggregate<<<(N * 64 + 255) / 256, 256, 0, stream>>>(
        (const unsigned int*)xwb, offs, csr_src, dinv, b2, out, N);
}